// Round 4
// baseline (524.927 us; speedup 1.0000x reference)
//
#include <hip/hip_runtime.h>

#define HIDDEN 64
#define NREL 50
#define NPAIR (NREL * NREL)
#define CAP 32              // bucket capacity per edge: 32 x 2B = one 64B line.
                            // deg ~ Poisson(2); P(any of 1M buckets >= 32) ~ 1e-19.

typedef float v4f __attribute__((ext_vector_type(4)));

// ---------------------------------------------------------------------------
// Kernel 1: precompute tables + zero the per-edge counters (fused).
//   M2[p][j] = sum_k relu( sum_i pair_p[i] * W_msg[i][k] ) * W_upd[64+k][j]
//   Hc[r][j] = sum_i rel_emb[r][i] * W_upd[i][j]
// ---------------------------------------------------------------------------
__global__ void precompute_tables(const float* __restrict__ rel_emb,
                                  const float* __restrict__ W_msg,
                                  const float* __restrict__ W_upd,
                                  float* __restrict__ M2,
                                  float* __restrict__ Hc,
                                  int* __restrict__ counts, int num_edge) {
    const int p = blockIdx.x;      // 0..2499
    const int j = threadIdx.x;     // 0..63

    // zero counts (grid-stride across the whole dispatch; ~6 ints/thread)
    {
        const int gstride = gridDim.x * blockDim.x;
        for (int i = blockIdx.x * blockDim.x + threadIdx.x; i < num_edge; i += gstride)
            counts[i] = 0;
    }

    const int ra = p / NREL, rb = p % NREL;
    __shared__ float msg[HIDDEN];
    const float* ha = rel_emb + ra * HIDDEN;
    const float* hb = rel_emb + rb * HIDDEN;

    float acc = 0.f;
    #pragma unroll 8
    for (int i = 0; i < HIDDEN; ++i) acc += ha[i] * W_msg[i * HIDDEN + j];
    #pragma unroll 8
    for (int i = 0; i < HIDDEN; ++i) acc += hb[i] * W_msg[(HIDDEN + i) * HIDDEN + j];
    msg[j] = fmaxf(acc, 0.f);
    __syncthreads();

    float acc2 = 0.f;
    #pragma unroll 8
    for (int k = 0; k < HIDDEN; ++k) acc2 += msg[k] * W_upd[(HIDDEN + k) * HIDDEN + j];
    M2[p * HIDDEN + j] = acc2;

    if (p < NREL) {
        float acc3 = 0.f;
        #pragma unroll 8
        for (int i = 0; i < HIDDEN; ++i) acc3 += rel_emb[p * HIDDEN + i] * W_upd[i * HIDDEN + j];
        Hc[p * HIDDEN + j] = acc3;
    }
}

// ---------------------------------------------------------------------------
// Kernel 2: direct bucketing. rank = atomicAdd(counts[ac]); one scattered 2B
// store per triangle into the edge's private 64B bucket line. int4 batching
// gives 4 independent chains per thread for latency overlap.
// ---------------------------------------------------------------------------
__global__ void hist_direct(const int* __restrict__ rel,
                            const int* __restrict__ edge_ab,
                            const int* __restrict__ edge_bc,
                            const int* __restrict__ edge_ac,
                            int* __restrict__ counts,
                            unsigned short* __restrict__ bucket, int num_tri) {
    const int n4 = num_tri >> 2;
    const int stride = gridDim.x * blockDim.x;
    int i = blockIdx.x * blockDim.x + threadIdx.x;
    for (; i < n4; i += stride) {
        const int4 a = ((const int4*)edge_ab)[i];
        const int4 b = ((const int4*)edge_bc)[i];
        const int4 c = ((const int4*)edge_ac)[i];
        // 8 independent gathers into the 4 MB rel array (L2-resident)
        const int p0 = rel[a.x] * NREL + rel[b.x];
        const int p1 = rel[a.y] * NREL + rel[b.y];
        const int p2 = rel[a.z] * NREL + rel[b.z];
        const int p3 = rel[a.w] * NREL + rel[b.w];
        // 4 independent atomics (same-address pairs still get distinct ranks)
        const int r0 = atomicAdd(&counts[c.x], 1);
        const int r1 = atomicAdd(&counts[c.y], 1);
        const int r2 = atomicAdd(&counts[c.z], 1);
        const int r3 = atomicAdd(&counts[c.w], 1);
        if ((unsigned)r0 < (unsigned)CAP) bucket[(size_t)c.x * CAP + r0] = (unsigned short)p0;
        if ((unsigned)r1 < (unsigned)CAP) bucket[(size_t)c.y * CAP + r1] = (unsigned short)p1;
        if ((unsigned)r2 < (unsigned)CAP) bucket[(size_t)c.z * CAP + r2] = (unsigned short)p2;
        if ((unsigned)r3 < (unsigned)CAP) bucket[(size_t)c.w * CAP + r3] = (unsigned short)p3;
    }
    // tail (num_tri not divisible by 4)
    const int tail = n4 << 2;
    for (int t = tail + blockIdx.x * blockDim.x + threadIdx.x; t < num_tri; t += stride) {
        const int p = rel[edge_ab[t]] * NREL + rel[edge_bc[t]];
        const int ac = edge_ac[t];
        const int r = atomicAdd(&counts[ac], 1);
        if ((unsigned)r < (unsigned)CAP) bucket[(size_t)ac * CAP + r] = (unsigned short)p;
    }
}

// ---------------------------------------------------------------------------
// Kernel 3: per-edge gather-accumulate + fused update.
// 16 lanes (float4 each) per edge; 16 edges per 256-thread block -> the
// block's out writes are one contiguous 4 KB span. Bucket entries read as
// aligned ushort2 (2 triangles per load); M2 rows are L1/L2-hot (640 KB).
// Non-temporal out store keeps M2/bucket lines resident in L2.
// ---------------------------------------------------------------------------
__global__ void accumulate(const int* __restrict__ rel,
                           const int* __restrict__ counts,
                           const unsigned short* __restrict__ bucket,
                           const float* __restrict__ M2,
                           const float* __restrict__ Hc,
                           float* __restrict__ out, int num_edge) {
    const int sub = threadIdx.x >> 4;   // 0..15: edge slot within block
    const int l   = threadIdx.x & 15;   // float4 lane within row
    int e = blockIdx.x * 16 + sub;
    const int estride = gridDim.x * 16;
    for (; e < num_edge; e += estride) {
        const int c = min(counts[e], CAP);
        const int r = rel[e];
        const ushort2* row = (const ushort2*)(bucket + (size_t)e * CAP);
        const v4f h = ((const v4f*)(Hc + r * HIDDEN))[l];

        v4f a0 = {0.f, 0.f, 0.f, 0.f};
        v4f a1 = {0.f, 0.f, 0.f, 0.f};
        int k = 0;
        for (; k + 2 <= c; k += 2) {
            const ushort2 pp = row[k >> 1];          // one 4B load, 2 pair-ids
            const v4f m0 = ((const v4f*)M2)[(int)pp.x * 16 + l];
            const v4f m1 = ((const v4f*)M2)[(int)pp.y * 16 + l];
            a0 += m0;
            a1 += m1;
        }
        if (k < c) {
            const int p = bucket[(size_t)e * CAP + k];
            a0 += ((const v4f*)M2)[p * 16 + l];
        }
        v4f o = a0 + a1 + h;
        o.x = fmaxf(o.x, 0.f);
        o.y = fmaxf(o.y, 0.f);
        o.z = fmaxf(o.z, 0.f);
        o.w = fmaxf(o.w, 0.f);
        __builtin_nontemporal_store(o, &((v4f*)out)[(size_t)e * 16 + l]);
    }
}

// --------------------------- fallback (round-1) path -----------------------
__global__ void scatter_tri(const int* __restrict__ rel,
                            const int* __restrict__ edge_ab,
                            const int* __restrict__ edge_bc,
                            const int* __restrict__ edge_ac,
                            const float* __restrict__ M2,
                            float* __restrict__ out, int num_tri) {
    const int lane   = threadIdx.x & 63;
    const int wave   = (int)((blockIdx.x * blockDim.x + threadIdx.x) >> 6);
    const int nwaves = (int)((gridDim.x * blockDim.x) >> 6);
    for (int t = wave; t < num_tri; t += nwaves) {
        const int p = rel[edge_ab[t]] * NREL + rel[edge_bc[t]];
        const float v = M2[p * HIDDEN + lane];
        unsafeAtomicAdd(&out[(size_t)edge_ac[t] * HIDDEN + lane], v);
    }
}

__global__ void finalize(const int* __restrict__ rel,
                         const float* __restrict__ Hc,
                         float* __restrict__ out, int num_edge) {
    const int total = num_edge * (HIDDEN / 4);
    int i = blockIdx.x * blockDim.x + threadIdx.x;
    const int stride = gridDim.x * blockDim.x;
    for (; i < total; i += stride) {
        const int e = i >> 4;
        const int q = i & 15;
        float4 a = ((const float4*)out)[i];
        float4 h = ((const float4*)(Hc + rel[e] * HIDDEN))[q];
        float4 o;
        o.x = fmaxf(a.x + h.x, 0.f);
        o.y = fmaxf(a.y + h.y, 0.f);
        o.z = fmaxf(a.z + h.z, 0.f);
        o.w = fmaxf(a.w + h.w, 0.f);
        ((float4*)out)[i] = o;
    }
}
// ---------------------------------------------------------------------------

extern "C" void kernel_launch(void* const* d_in, const int* in_sizes, int n_in,
                              void* d_out, int out_size, void* d_ws, size_t ws_size,
                              hipStream_t stream) {
    const float* rel_emb = (const float*)d_in[0];
    const float* W_msg   = (const float*)d_in[1];
    const float* W_upd   = (const float*)d_in[2];
    const int* rel     = (const int*)d_in[5];
    const int* edge_ab = (const int*)d_in[6];
    const int* edge_bc = (const int*)d_in[7];
    const int* edge_ac = (const int*)d_in[8];
    float* out = (float*)d_out;

    const int num_edge = in_sizes[5];
    const int num_tri  = in_sizes[6];

    // ---- workspace layout (256B-aligned offsets) ----
    char* ws = (char*)d_ws;
    size_t off = 0;
    auto alloc = [&](size_t bytes) { char* p = ws + off; off = (off + bytes + 255) & ~(size_t)255; return p; };
    float*          M2     = (float*)alloc((size_t)NPAIR * HIDDEN * 4);          // 640 KB
    float*          Hc     = (float*)alloc((size_t)NREL * HIDDEN * 4);           // 12.8 KB
    int*            counts = (int*)alloc((size_t)num_edge * 4);                  // 4 MB
    unsigned short* bucket = (unsigned short*)alloc((size_t)num_edge * CAP * 2); // 64 MB
    const size_t required = off;

    if (ws_size >= required) {
        // ---- 3-dispatch direct-bucket path ----
        precompute_tables<<<NPAIR, HIDDEN, 0, stream>>>(rel_emb, W_msg, W_upd,
                                                        M2, Hc, counts, num_edge);
        hist_direct<<<2048, 256, 0, stream>>>(rel, edge_ab, edge_bc, edge_ac,
                                              counts, bucket, num_tri);
        const int ablocks = (num_edge + 15) / 16;
        accumulate<<<ablocks, 256, 0, stream>>>(rel, counts, bucket, M2, Hc, out, num_edge);
    } else {
        // ---- fallback: round-1 atomic path ----
        precompute_tables<<<NPAIR, HIDDEN, 0, stream>>>(rel_emb, W_msg, W_upd,
                                                        M2, Hc, counts,
                                                        num_edge < 1 ? 1 : 1);
        hipMemsetAsync(d_out, 0, (size_t)out_size * sizeof(float), stream);
        scatter_tri<<<8192, 256, 0, stream>>>(rel, edge_ab, edge_bc, edge_ac, M2, out, num_tri);
        const int total4 = num_edge * (HIDDEN / 4);
        int fin_blocks = (total4 + 255) / 256;
        if (fin_blocks > 65535 * 8) fin_blocks = 65535 * 8;
        finalize<<<fin_blocks, 256, 0, stream>>>(rel, Hc, out, num_edge);
    }
}